// Round 7
// baseline (200.793 us; speedup 1.0000x reference)
//
#include <hip/hip_runtime.h>

// InteractionBlock (ViT-Adapter injector+extractor with MSDeformAttn) for MI355X.
// R7: big GEMM single-buffered 32KB LDS (5 blocks/CU, m97 discipline, m132
// lesson: occupancy > in-block dbuf). XOR swizzle, nt-major, XCD swz kept.

#define LQ_VIT 2304
#define NA_ADA 12096

typedef float f32x4 __attribute__((ext_vector_type(4)));
typedef short bf16x8 __attribute__((ext_vector_type(8)));

__device__ __forceinline__ unsigned short f2bf(float f) {
  unsigned u = __builtin_bit_cast(unsigned, f);
  u += 0x7FFFu + ((u >> 16) & 1u);   // round-to-nearest-even bf16
  return (unsigned short)(u >> 16);
}
__device__ __forceinline__ float bf2f(unsigned short u) {
  return __builtin_bit_cast(float, (unsigned)u << 16);
}
__device__ __forceinline__ f32x4 ld4bf(const unsigned short* p) {
  ushort4 t = *(const ushort4*)p;
  f32x4 r; r[0] = bf2f(t.x); r[1] = bf2f(t.y); r[2] = bf2f(t.z); r[3] = bf2f(t.w);
  return r;
}

__device__ __forceinline__ void gload_lds16(const void* g, void* l) {
  __builtin_amdgcn_global_load_lds(
      (__attribute__((address_space(1))) void*)(void*)g,
      (__attribute__((address_space(3))) void*)l, 16, 0, 0);
}

// ================= fused prep kernel =========================================
// block ranges: [0,2568) weight transpose+cast; [2568,4616) adapter cast;
// [4616,5192) vit LN; [5192] bias concat.
struct PrepPack {
  const float* W[8];
  unsigned short* WT[8];
  int N[8];
  int cum[9];  // cumulative nb (N/32 tiles)
  const float* adapter; unsigned short* adbf; int n4;
  const float* vit; const float* qg; const float* qb; unsigned short* qln;
  const float* isv; const float* iav; const float* ibv;
  const float* esv; const float* eav;
  float* bci; float* bbig;
};

__global__ __launch_bounds__(256) void prep_kernel(PrepPack pp) {
  int b = blockIdx.x;
  int tid = threadIdx.x;
  if (b < 2568) {  // ---- transpose: W[768,N] f32 -> WT[N,768] bf16
    int kb = b / 107, col = b % 107;
    int z = 0;
#pragma unroll
    for (int i = 0; i < 8; i++) if (col >= pp.cum[i + 1]) z = i + 1;
    int nb = col - pp.cum[z];
    const float* __restrict__ W = pp.W[z];
    unsigned short* __restrict__ WT = pp.WT[z];
    int N = pp.N[z];
    int kb32 = kb * 32, nb32 = nb * 32;
    __shared__ float tile[32][33];
    int tx = tid & 31, ty = tid >> 5;  // 8 rows stride
    for (int i = ty; i < 32; i += 8) {
      int n = nb32 + tx;
      tile[i][tx] = (n < N) ? W[(size_t)(kb32 + i) * N + n] : 0.f;
    }
    __syncthreads();
    for (int i = ty; i < 32; i += 8) {
      int n = nb32 + i, k = kb32 + tx;
      if (n < N) WT[(size_t)n * 768 + k] = f2bf(tile[tx][i]);
    }
  } else if (b < 4616) {  // ---- adapter f32 -> bf16 (grid-stride float4)
    for (int i = (b - 2568) * 256 + tid; i < pp.n4; i += 2048 * 256) {
      float4 v = ((const float4*)pp.adapter)[i];
      ushort4 o;
      o.x = f2bf(v.x); o.y = f2bf(v.y); o.z = f2bf(v.z); o.w = f2bf(v.w);
      ((ushort4*)pp.adbf)[i] = o;
    }
  } else if (b < 5192) {  // ---- vit LN -> bf16
    int wid = (b - 4616) * 4 + (tid >> 6);
    int lane = tid & 63;
    if (wid >= LQ_VIT) return;
    const float* row = pp.vit + (size_t)wid * 768;
    float x[12]; float s = 0.f;
#pragma unroll
    for (int j = 0; j < 12; j++) { x[j] = row[lane + j * 64]; s += x[j]; }
#pragma unroll
    for (int o = 32; o >= 1; o >>= 1) s += __shfl_xor(s, o);
    float mean = s * (1.f / 768.f);
    float v = 0.f;
#pragma unroll
    for (int j = 0; j < 12; j++) { float d = x[j] - mean; v += d * d; }
#pragma unroll
    for (int o = 32; o >= 1; o >>= 1) v += __shfl_xor(v, o);
    float rs = rsqrtf(v * (1.f / 768.f) + 1e-6f);
#pragma unroll
    for (int j = 0; j < 12; j++) {
      int c = lane + j * 64;
      pp.qln[(size_t)wid * 768 + c] = f2bf((x[j] - mean) * rs * pp.qg[c] + pp.qb[c]);
    }
  } else {  // ---- bias concat
    for (int i = tid; i < 840; i += 256) {
      if (i < 144) pp.bci[i] = pp.isv[i];
      else if (i < 216) pp.bci[i] = pp.iav[i - 144];
      if (i < 768) pp.bbig[i] = pp.ibv[i];
      else if (i < 816) pp.bbig[i] = pp.esv[i - 768];
      else pp.bbig[i] = pp.eav[i - 816];
    }
  }
}

// ================= big GEMM: BM=128, BN=128, BK=64, SINGLE-buffered ==========
// C[M,N] bf16 = A[M,K]bf16 @ BT[N,K]^T + bias. 4 waves, 64x64/wave (FM=FN=4).
// 32KB LDS -> 5 blocks/CU; cross-block TLP hides the per-K-step vmcnt drain
// (m97/m114 mechanism). kk-split compute halves live frag VGPRs.
struct GemmTask {
  const unsigned short* A; const unsigned short* BT;
  const float* bias; unsigned short* C;
  int M, N, NT, nwg;
};

__global__ __launch_bounds__(256) void gemm_big_kernel(GemmTask t0, GemmTask t1, int split) {
  __shared__ unsigned short lds[(128 + 128) * 64];  // 32KB single buffer

  GemmTask tk = (blockIdx.x < split) ? t0 : t1;
  int id = (blockIdx.x < split) ? blockIdx.x : blockIdx.x - split;
  // bijective XCD swizzle over this task's nwg
  int nwg = tk.nwg;
  int qq = nwg >> 3, rr = nwg & 7;
  int xcd = id & 7, idx = id >> 3;
  int wg = (xcd < rr ? xcd * (qq + 1) : rr * (qq + 1) + (xcd - rr) * qq) + idx;
  int nt = wg % tk.NT, mt = wg / tk.NT;     // nt-major: A-tile reused across nt
  int m0 = mt * 128, n0 = nt * 128;
  int M = tk.M, N = tk.N;
  const unsigned short* __restrict__ A = tk.A;
  const unsigned short* __restrict__ BT = tk.BT;
  const int K = 768, kT = 12;

  int tid = threadIdx.x;
  int w = tid >> 6, lane = tid & 63;
  int wr = w >> 1, wc = w & 1;
  int frow = lane & 15, ghi = lane >> 4;
  int l7 = lane & 7;
  int sr = lane >> 3;
  int sgx = ((l7 ^ sr) * 8);            // staging source granule (elems)
  int gx0 = ((ghi ^ l7) * 8);           // read granule kk=0
  int gx1 = (((4 + ghi) ^ l7) * 8);     // read granule kk=32

  f32x4 acc[4][4] = {};

  auto stage = [&](int k0) {
#pragma unroll
    for (int i = 0; i < 8; i++) {
      int c = w * 8 + i;                // 32 chunks: 16 A + 16 B, 1KB each
      if (c < 16) {
        int gm = m0 + c * 8 + sr; if (gm >= M) gm = M - 1;
        gload_lds16(&A[(size_t)gm * K + k0 + sgx], &lds[c * 512]);
      } else {
        int gn = n0 + (c - 16) * 8 + sr; if (gn >= N) gn = N - 1;
        gload_lds16(&BT[(size_t)gn * K + k0 + sgx], &lds[c * 512]);
      }
    }
  };

  for (int t = 0; t < kT; t++) {
    __syncthreads();                   // previous tile's readers done
    stage(t << 6);
    __syncthreads();                   // tile resident (vmcnt drained in barrier)
    const unsigned short* As_ = lds;
    const unsigned short* Bs_ = lds + 16 * 512;
    {
      bf16x8 af[4], bg[4];
#pragma unroll
      for (int m = 0; m < 4; m++)
        af[m] = *(const bf16x8*)&As_[(wr * 64 + m * 16 + frow) * 64 + gx0];
#pragma unroll
      for (int n = 0; n < 4; n++)
        bg[n] = *(const bf16x8*)&Bs_[(wc * 64 + n * 16 + frow) * 64 + gx0];
#pragma unroll
      for (int m = 0; m < 4; m++)
#pragma unroll
        for (int n = 0; n < 4; n++)
          acc[m][n] = __builtin_amdgcn_mfma_f32_16x16x32_bf16(af[m], bg[n], acc[m][n], 0, 0, 0);
    }
    {
      bf16x8 af[4], bg[4];
#pragma unroll
      for (int m = 0; m < 4; m++)
        af[m] = *(const bf16x8*)&As_[(wr * 64 + m * 16 + frow) * 64 + gx1];
#pragma unroll
      for (int n = 0; n < 4; n++)
        bg[n] = *(const bf16x8*)&Bs_[(wc * 64 + n * 16 + frow) * 64 + gx1];
#pragma unroll
      for (int m = 0; m < 4; m++)
#pragma unroll
        for (int n = 0; n < 4; n++)
          acc[m][n] = __builtin_amdgcn_mfma_f32_16x16x32_bf16(af[m], bg[n], acc[m][n], 0, 0, 0);
    }
  }

  int orow = (lane >> 4) * 4, ocol = lane & 15;
  unsigned short* C = tk.C;
  const float* bias = tk.bias;
#pragma unroll
  for (int m = 0; m < 4; m++) {
    int gmb = m0 + wr * 64 + m * 16 + orow;
#pragma unroll
    for (int n = 0; n < 4; n++) {
      int gn = n0 + wc * 64 + n * 16 + ocol;
      if (gn < N) {
        float bv = bias[gn];
#pragma unroll
        for (int r = 0; r < 4; r++) {
          int gm = gmb + r;
          if (gm < M) C[(size_t)gm * N + gn] = f2bf(acc[m][n][r] + bv);
        }
      }
    }
  }
}

// ================= mid GEMM: BM=64, BN=128, 2-phase (1 block/CU regime) ======
__global__ __launch_bounds__(256) void gemm_mid_kernel(
    const unsigned short* __restrict__ A, const unsigned short* __restrict__ BT,
    const float* __restrict__ bias, unsigned short* __restrict__ C,
    int M, int N, int NT) {
  __shared__ unsigned short lds[2][(64 + 128) * 64];  // 2 x 24KB

  int nwg = gridDim.x;
  int id = blockIdx.x;
  int qq = nwg >> 3, rr = nwg & 7;
  int xcd = id & 7, idx = id >> 3;
  int wg = (xcd < rr ? xcd * (qq + 1) : rr * (qq + 1) + (xcd - rr) * qq) + idx;
  int nt = wg % NT, mt = wg / NT;
  int m0 = mt * 64, n0 = nt * 128;
  const int K = 768, kT = 12;

  int tid = threadIdx.x;
  int w = tid >> 6, lane = tid & 63;
  int frow = lane & 15, ghi = lane >> 4;
  int l7 = lane & 7;
  int sr = lane >> 3;
  int sgx = ((l7 ^ sr) * 8);
  int gx0 = ((ghi ^ l7) * 8);
  int gx1 = (((4 + ghi) ^ l7) * 8);

  f32x4 acc[4][2] = {};

  auto stage = [&](unsigned short* dst, int k0) {
#pragma unroll
    for (int i = 0; i < 6; i++) {
      int c = w * 6 + i;                // 24 chunks: 8 A + 16 B
      if (c < 8) {
        int gm = m0 + c * 8 + sr; if (gm >= M) gm = M - 1;
        gload_lds16(&A[(size_t)gm * K + k0 + sgx], &dst[c * 512]);
      } else {
        int gn = n0 + (c - 8) * 8 + sr; if (gn >= N) gn = N - 1;
        gload_lds16(&BT[(size_t)gn * K + k0 + sgx], &dst[c * 512]);
      }
    }
  };

  unsigned short* b0 = &lds[0][0];
  unsigned short* b1 = &lds[1][0];
  stage(b0, 0);
  __syncthreads();

  for (int t = 0; t < kT; t++) {
    unsigned short* cb = (t & 1) ? b1 : b0;
    unsigned short* nb = (t & 1) ? b0 : b1;
    if (t + 1 < kT) stage(nb, (t + 1) << 6);
    const unsigned short* As_ = cb;
    const unsigned short* Bs_ = cb + 8 * 512;
    bf16x8 af0[4], af1[4], bg0[2], bg1[2];
#pragma unroll
    for (int m = 0; m < 4; m++) {
      int r = m * 16 + frow;
      af0[m] = *(const bf16x8*)&As_[r * 64 + gx0];
      af1[m] = *(const bf16x8*)&As_[r * 64 + gx1];
    }
#pragma unroll
    for (int n = 0; n < 2; n++) {
      int r = w * 32 + n * 16 + frow;
      bg0[n] = *(const bf16x8*)&Bs_[r * 64 + gx0];
      bg1[n] = *(const bf16x8*)&Bs_[r * 64 + gx1];
    }
#pragma unroll
    for (int m = 0; m < 4; m++)
#pragma unroll
      for (int n = 0; n < 2; n++) {
        acc[m][n] = __builtin_amdgcn_mfma_f32_16x16x32_bf16(af0[m], bg0[n], acc[m][n], 0, 0, 0);
        acc[m][n] = __builtin_amdgcn_mfma_f32_16x16x32_bf16(af1[m], bg1[n], acc[m][n], 0, 0, 0);
      }
    __syncthreads();
  }

  int orow = (lane >> 4) * 4, ocol = lane & 15;
#pragma unroll
  for (int m = 0; m < 4; m++) {
    int gmb = m0 + m * 16 + orow;
#pragma unroll
    for (int n = 0; n < 2; n++) {
      int gn = n0 + w * 32 + n * 16 + ocol;
      if (gn < N) {
        float bv = bias[gn];
#pragma unroll
        for (int r = 0; r < 4; r++) {
          int gm = gmb + r;
          if (gm < M) C[(size_t)gm * N + gn] = f2bf(acc[m][n][r] + bv);
        }
      }
    }
  }
}

// ---------------- fused residual + LayerNorm (attn in bf16) ------------------
__global__ __launch_bounds__(256) void residual_ln_kernel(
    const float* __restrict__ vit, const unsigned short* __restrict__ attn,
    const float* __restrict__ gamma, const float* __restrict__ g,
    const float* __restrict__ b, float* __restrict__ vout,
    unsigned short* __restrict__ vln, int R) {
  int wid = blockIdx.x * 4 + (threadIdx.x >> 6);
  int lane = threadIdx.x & 63;
  if (wid >= R) return;
  const float* ra = vit + (size_t)wid * 768;
  const unsigned short* rb = attn + (size_t)wid * 768;
  float x[12]; float s = 0.f;
#pragma unroll
  for (int j = 0; j < 12; j++) {
    int c = lane + j * 64;
    x[j] = ra[c] + gamma[c] * bf2f(rb[c]);
    vout[(size_t)wid * 768 + c] = x[j];
    s += x[j];
  }
#pragma unroll
  for (int o = 32; o >= 1; o >>= 1) s += __shfl_xor(s, o);
  float mean = s * (1.f / 768.f);
  float v = 0.f;
#pragma unroll
  for (int j = 0; j < 12; j++) { float d = x[j] - mean; v += d * d; }
#pragma unroll
  for (int o = 32; o >= 1; o >>= 1) v += __shfl_xor(v, o);
  float rs = rsqrtf(v * (1.f / 768.f) + 1e-6f);
#pragma unroll
  for (int j = 0; j < 12; j++) {
    int c = lane + j * 64;
    vln[(size_t)wid * 768 + c] = f2bf((x[j] - mean) * rs * g[c] + b[c]);
  }
}

// ---------------- add + LayerNorm -> f32 out (Xb in bf16) --------------------
__global__ __launch_bounds__(256) void add_ln_f32_kernel(
    const float* __restrict__ Xa, const unsigned short* __restrict__ Xb,
    const float* __restrict__ g, const float* __restrict__ b,
    float* __restrict__ out, int R) {
  int wid = blockIdx.x * 4 + (threadIdx.x >> 6);
  int lane = threadIdx.x & 63;
  if (wid >= R) return;
  const float* ra = Xa + (size_t)wid * 768;
  const unsigned short* rb = Xb + (size_t)wid * 768;
  float x[12]; float s = 0.f;
#pragma unroll
  for (int j = 0; j < 12; j++) {
    int c = lane + j * 64;
    x[j] = ra[c] + bf2f(rb[c]); s += x[j];
  }
#pragma unroll
  for (int o = 32; o >= 1; o >>= 1) s += __shfl_xor(s, o);
  float mean = s * (1.f / 768.f);
  float v = 0.f;
#pragma unroll
  for (int j = 0; j < 12; j++) { float d = x[j] - mean; v += d * d; }
#pragma unroll
  for (int o = 32; o >= 1; o >>= 1) v += __shfl_xor(v, o);
  float rs = rsqrtf(v * (1.f / 768.f) + 1e-6f);
#pragma unroll
  for (int j = 0; j < 12; j++) {
    int c = lane + j * 64;
    out[(size_t)wid * 768 + c] = (x[j] - mean) * rs * g[c] + b[c];
  }
}

// ---------------- deformable samplers (bf16 tensors) -------------------------
__global__ __launch_bounds__(256) void sampler_inj_kernel(
    const float* __restrict__ ref, const unsigned short* __restrict__ sa,
    const unsigned short* __restrict__ v, unsigned short* __restrict__ out, int vst) {
  int gw = (blockIdx.x * 256 + threadIdx.x) >> 6;
  int lane = threadIdx.x & 63;
  int q = gw / 3, hp = gw - q * 3;
  if (q >= LQ_VIT) return;
  int h = hp * 2 + (lane >> 5);
  int c = h * 128 + (lane & 31) * 4;
  float rx = ref[q * 2], ry = ref[q * 2 + 1];
  const unsigned short* row = sa + (size_t)q * 216;
  float lg[12]; float mx = -1e30f;
#pragma unroll
  for (int i = 0; i < 12; i++) { lg[i] = bf2f(row[144 + h * 12 + i]); mx = fmaxf(mx, lg[i]); }
  float s = 0.f;
#pragma unroll
  for (int i = 0; i < 12; i++) { lg[i] = __expf(lg[i] - mx); s += lg[i]; }
  float inv = 1.f / s;
  f32x4 acc = {0.f, 0.f, 0.f, 0.f};
  const int LW[3] = {96, 48, 24};
  const int LS[3] = {0, 9216, 11520};
#pragma unroll
  for (int l = 0; l < 3; l++) {
    const int Wl = LW[l], st = LS[l], Wm = Wl - 1;
    const float Wf = (float)Wl;
#pragma unroll
    for (int p = 0; p < 4; p++) {
      int ob = ((h * 3 + l) * 4 + p) * 2;
      float ix = fmaf(rx, Wf, bf2f(row[ob])) - 0.5f;
      float iy = fmaf(ry, Wf, bf2f(row[ob + 1])) - 0.5f;
      float x0f = floorf(ix), y0f = floorf(iy);
      float wx = ix - x0f, wy = iy - y0f;
      int x0 = (int)x0f, y0 = (int)y0f;
      float aw = lg[l * 4 + p] * inv;
      float wy0 = (1.f - wy) * aw, wy1 = wy * aw;
      float w00 = (1.f - wx) * wy0, w01 = wx * wy0;
      float w10 = (1.f - wx) * wy1, w11 = wx * wy1;
      bool xv0 = (unsigned)x0 < (unsigned)Wl, xv1 = (unsigned)(x0 + 1) < (unsigned)Wl;
      bool yv0 = (unsigned)y0 < (unsigned)Wl, yv1 = (unsigned)(y0 + 1) < (unsigned)Wl;
      w00 = (xv0 && yv0) ? w00 : 0.f;
      w01 = (xv1 && yv0) ? w01 : 0.f;
      w10 = (xv0 && yv1) ? w10 : 0.f;
      w11 = (xv1 && yv1) ? w11 : 0.f;
      int x0c = min(max(x0, 0), Wm), x1c = min(max(x0 + 1, 0), Wm);
      int y0c = min(max(y0, 0), Wm), y1c = min(max(y0 + 1, 0), Wm);
      const unsigned short* r0 = v + ((size_t)(st + y0c * Wl) * vst + c);
      const unsigned short* r1 = v + ((size_t)(st + y1c * Wl) * vst + c);
      acc += w00 * ld4bf(r0 + (size_t)x0c * vst) + w01 * ld4bf(r0 + (size_t)x1c * vst)
           + w10 * ld4bf(r1 + (size_t)x0c * vst) + w11 * ld4bf(r1 + (size_t)x1c * vst);
    }
  }
  ushort4 o4;
  o4.x = f2bf(acc[0]); o4.y = f2bf(acc[1]); o4.z = f2bf(acc[2]); o4.w = f2bf(acc[3]);
  *(ushort4*)&out[(size_t)q * 768 + c] = o4;
}

__global__ __launch_bounds__(256) void sampler_ext_kernel(
    const float* __restrict__ ref, const unsigned short* __restrict__ sa, int sst,
    const unsigned short* __restrict__ v, unsigned short* __restrict__ out) {
  int gw = (blockIdx.x * 256 + threadIdx.x) >> 6;
  int lane = threadIdx.x & 63;
  int q = gw / 3, hp = gw - q * 3;
  if (q >= NA_ADA) return;
  int h = hp * 2 + (lane >> 5);
  int c = h * 128 + (lane & 31) * 4;
  float rx = ref[q * 2], ry = ref[q * 2 + 1];
  const unsigned short* row = sa + (size_t)q * sst;
  float lg[4]; float mx = -1e30f;
#pragma unroll
  for (int p = 0; p < 4; p++) { lg[p] = bf2f(row[48 + h * 4 + p]); mx = fmaxf(mx, lg[p]); }
  float s = 0.f;
#pragma unroll
  for (int p = 0; p < 4; p++) { lg[p] = __expf(lg[p] - mx); s += lg[p]; }
  float inv = 1.f / s;
  f32x4 acc = {0.f, 0.f, 0.f, 0.f};
#pragma unroll
  for (int p = 0; p < 4; p++) {
    int ob = (h * 4 + p) * 2;
    float ix = fmaf(rx, 48.f, bf2f(row[ob])) - 0.5f;
    float iy = fmaf(ry, 48.f, bf2f(row[ob + 1])) - 0.5f;
    float x0f = floorf(ix), y0f = floorf(iy);
    float wx = ix - x0f, wy = iy - y0f;
    int x0 = (int)x0f, y0 = (int)y0f;
    float aw = lg[p] * inv;
    float wy0 = (1.f - wy) * aw, wy1 = wy * aw;
    float w00 = (1.f - wx) * wy0, w01 = wx * wy0;
    float w10 = (1.f - wx) * wy1, w11 = wx * wy1;
    bool xv0 = (unsigned)x0 < 48u, xv1 = (unsigned)(x0 + 1) < 48u;
    bool yv0 = (unsigned)y0 < 48u, yv1 = (unsigned)(y0 + 1) < 48u;
    w00 = (xv0 && yv0) ? w00 : 0.f;
    w01 = (xv1 && yv0) ? w01 : 0.f;
    w10 = (xv0 && yv1) ? w10 : 0.f;
    w11 = (xv1 && yv1) ? w11 : 0.f;
    int x0c = min(max(x0, 0), 47), x1c = min(max(x0 + 1, 0), 47);
    int y0c = min(max(y0, 0), 47), y1c = min(max(y0 + 1, 0), 47);
    const unsigned short* r0 = v + ((size_t)(y0c * 48) * 768 + c);
    const unsigned short* r1 = v + ((size_t)(y1c * 48) * 768 + c);
    acc += w00 * ld4bf(r0 + (size_t)x0c * 768) + w01 * ld4bf(r0 + (size_t)x1c * 768)
         + w10 * ld4bf(r1 + (size_t)x0c * 768) + w11 * ld4bf(r1 + (size_t)x1c * 768);
  }
  ushort4 o4;
  o4.x = f2bf(acc[0]); o4.y = f2bf(acc[1]); o4.z = f2bf(acc[2]); o4.w = f2bf(acc[3]);
  *(ushort4*)&out[(size_t)q * 768 + c] = o4;
}

extern "C" void kernel_launch(void* const* d_in, const int* in_sizes, int n_in,
                              void* d_out, int out_size, void* d_ws, size_t ws_size,
                              hipStream_t stream) {
  (void)in_sizes; (void)n_in; (void)out_size; (void)ws_size;
  const float* vit      = (const float*)d_in[0];
  const float* adapter  = (const float*)d_in[1];
  const float* ref1     = (const float*)d_in[2];
  const float* ref2     = (const float*)d_in[3];
  const float* inj_qn_g = (const float*)d_in[4];
  const float* inj_qn_b = (const float*)d_in[5];
  const float* inj_Wv   = (const float*)d_in[6];
  const float* inj_bv   = (const float*)d_in[7];
  const float* inj_Ws   = (const float*)d_in[8];
  const float* inj_bs   = (const float*)d_in[9];
  const float* inj_Wa   = (const float*)d_in[10];
  const float* inj_ba   = (const float*)d_in[11];
  const float* inj_Wo   = (const float*)d_in[12];
  const float* inj_bo   = (const float*)d_in[13];
  const float* inj_gamma= (const float*)d_in[14];
  const float* ext_vn_g = (const float*)d_in[15];
  const float* ext_vn_b = (const float*)d_in[16];
  const float* ext_qn_g = (const float*)d_in[17];
  const float* ext_qn_b = (const float*)d_in[18];
  const float* ext_Wv   = (const float*)d_in[19];
  const float* ext_bv   = (const float*)d_in[20];
  const float* ext_Ws   = (const float*)d_in[21];
  const float* ext_bs   = (const float*)d_in[22];
  const float* ext_Wa   = (const float*)d_in[23];
  const float* ext_ba   = (const float*)d_in[24];
  const float* ext_Wo   = (const float*)d_in[25];
  const float* ext_bo   = (const float*)d_in[26];

  size_t cur = 0;
  auto take = [&](size_t bytes) {
    void* p = (char*)d_ws + cur;
    cur += (bytes + 255) & ~(size_t)255;
    return p;
  };
  unsigned short* WBIG = (unsigned short*)take((size_t)840 * 768 * 2);
  unsigned short* WTIO = (unsigned short*)take((size_t)768 * 768 * 2);
  unsigned short* WTEV = (unsigned short*)take((size_t)768 * 768 * 2);
  unsigned short* WTEO = (unsigned short*)take((size_t)768 * 768 * 2);
  unsigned short* WSAI = (unsigned short*)take((size_t)216 * 768 * 2);
  float* BCI  = (float*)take((size_t)216 * 4);
  float* BBIG = (float*)take((size_t)840 * 4);
  unsigned short* ADBF = (unsigned short*)take((size_t)NA_ADA * 768 * 2);
  unsigned short* QLN  = (unsigned short*)take((size_t)LQ_VIT * 768 * 2);
  unsigned short* CBIG = (unsigned short*)take((size_t)NA_ADA * 840 * 2);  // [v_inj | sae]
  unsigned short* SAI  = (unsigned short*)take((size_t)LQ_VIT * 216 * 2);
  unsigned short* SAMPI= (unsigned short*)take((size_t)LQ_VIT * 768 * 2);
  unsigned short* ATTNI= (unsigned short*)take((size_t)LQ_VIT * 768 * 2);
  unsigned short* VLN  = (unsigned short*)take((size_t)LQ_VIT * 768 * 2);
  unsigned short* VEXT = (unsigned short*)take((size_t)LQ_VIT * 768 * 2);
  unsigned short* SAMPE = ADBF;   // adapter_bf16 dead after big GEMM 1
  unsigned short* ATTN2 = CBIG;   // CBIG dead after sampler_ext

  float* out_vit = (float*)d_out;
  float* out_ada = out_vit + (size_t)LQ_VIT * 768;

  PrepPack pp;
  pp.W[0] = inj_Wv; pp.WT[0] = WBIG;               pp.N[0] = 768;
  pp.W[1] = ext_Ws; pp.WT[1] = WBIG + 768 * 768;   pp.N[1] = 48;
  pp.W[2] = ext_Wa; pp.WT[2] = WBIG + 816 * 768;   pp.N[2] = 24;
  pp.W[3] = inj_Wo; pp.WT[3] = WTIO;               pp.N[3] = 768;
  pp.W[4] = ext_Wv; pp.WT[4] = WTEV;               pp.N[4] = 768;
  pp.W[5] = ext_Wo; pp.WT[5] = WTEO;               pp.N[5] = 768;
  pp.W[6] = inj_Ws; pp.WT[6] = WSAI;               pp.N[6] = 144;
  pp.W[7] = inj_Wa; pp.WT[7] = WSAI + 144 * 768;   pp.N[7] = 72;
  int cum = 0;
  for (int i = 0; i < 8; i++) { pp.cum[i] = cum; cum += (pp.N[i] + 31) / 32; }
  pp.cum[8] = cum;  // 107
  pp.adapter = adapter; pp.adbf = ADBF; pp.n4 = (NA_ADA * 768) / 4;
  pp.vit = vit; pp.qg = inj_qn_g; pp.qb = inj_qn_b; pp.qln = QLN;
  pp.isv = inj_bs; pp.iav = inj_ba; pp.ibv = inj_bv;
  pp.esv = ext_bs; pp.eav = ext_ba;
  pp.bci = BCI; pp.bbig = BBIG;
  prep_kernel<<<5193, 256, 0, stream>>>(pp);

  // launch 2: big GEMM 1 (v_inj + ext S/A, N=840) packed with SAI GEMM (N=216)
  GemmTask tA, tB;
  tA.A = ADBF; tA.BT = WBIG; tA.bias = BBIG; tA.C = CBIG;
  tA.M = NA_ADA; tA.N = 840; tA.NT = 7; tA.nwg = 95 * 7;
  tB.A = QLN; tB.BT = WSAI; tB.bias = BCI; tB.C = SAI;
  tB.M = LQ_VIT; tB.N = 216; tB.NT = 2; tB.nwg = 18 * 2;
  gemm_big_kernel<<<95 * 7 + 18 * 2, 256, 0, stream>>>(tA, tB, 95 * 7);

  sampler_inj_kernel<<<1728, 256, 0, stream>>>(ref1, SAI, CBIG, SAMPI, 840);

  gemm_mid_kernel<<<36 * 6, 256, 0, stream>>>(SAMPI, WTIO, inj_bo, ATTNI, LQ_VIT, 768, 6);
  residual_ln_kernel<<<576, 256, 0, stream>>>(vit, ATTNI, inj_gamma, ext_vn_g, ext_vn_b,
                                              out_vit, VLN, LQ_VIT);
  gemm_mid_kernel<<<36 * 6, 256, 0, stream>>>(VLN, WTEV, ext_bv, VEXT, LQ_VIT, 768, 6);

  sampler_ext_kernel<<<9072, 256, 0, stream>>>(ref2, CBIG + 768, 840, VEXT, SAMPE);

  GemmTask tC;
  tC.A = SAMPE; tC.BT = WTEO; tC.bias = ext_bo; tC.C = ATTN2;
  tC.M = NA_ADA; tC.N = 768; tC.NT = 6; tC.nwg = 95 * 6;
  gemm_big_kernel<<<95 * 6, 256, 0, stream>>>(tC, tC, 95 * 6);

  add_ln_f32_kernel<<<3024, 256, 0, stream>>>(adapter, ATTN2, ext_qn_g, ext_qn_b, out_ada, NA_ADA);
}

// Round 8
// 169.000 us; speedup vs baseline: 1.1881x; 1.1881x over previous
//
#include <hip/hip_runtime.h>

// InteractionBlock (ViT-Adapter injector+extractor with MSDeformAttn) for MI355X.
// R8: 3-buffer BK=32 pipelined GEMM with counted vmcnt(4) ledger — prefetch
// loads stay in flight ACROSS raw barriers (T3+T4 mechanism). While computing
// tile t: t+1 resident, t+2 in flight. Swizzle adapted to 32-elem rows.

#define LQ_VIT 2304
#define NA_ADA 12096

typedef float f32x4 __attribute__((ext_vector_type(4)));
typedef short bf16x8 __attribute__((ext_vector_type(8)));

__device__ __forceinline__ unsigned short f2bf(float f) {
  unsigned u = __builtin_bit_cast(unsigned, f);
  u += 0x7FFFu + ((u >> 16) & 1u);   // round-to-nearest-even bf16
  return (unsigned short)(u >> 16);
}
__device__ __forceinline__ float bf2f(unsigned short u) {
  return __builtin_bit_cast(float, (unsigned)u << 16);
}
__device__ __forceinline__ f32x4 ld4bf(const unsigned short* p) {
  ushort4 t = *(const ushort4*)p;
  f32x4 r; r[0] = bf2f(t.x); r[1] = bf2f(t.y); r[2] = bf2f(t.z); r[3] = bf2f(t.w);
  return r;
}

__device__ __forceinline__ void gload_lds16(const void* g, void* l) {
  __builtin_amdgcn_global_load_lds(
      (__attribute__((address_space(1))) void*)(void*)g,
      (__attribute__((address_space(3))) void*)l, 16, 0, 0);
}

#define FENCE() __builtin_amdgcn_sched_barrier(0)

// ================= fused prep kernel =========================================
struct PrepPack {
  const float* W[8];
  unsigned short* WT[8];
  int N[8];
  int cum[9];
  const float* adapter; unsigned short* adbf; int n4;
  const float* vit; const float* qg; const float* qb; unsigned short* qln;
  const float* isv; const float* iav; const float* ibv;
  const float* esv; const float* eav;
  float* bci; float* bbig;
};

__global__ __launch_bounds__(256) void prep_kernel(PrepPack pp) {
  int b = blockIdx.x;
  int tid = threadIdx.x;
  if (b < 2568) {  // ---- transpose: W[768,N] f32 -> WT[N,768] bf16
    int kb = b / 107, col = b % 107;
    int z = 0;
#pragma unroll
    for (int i = 0; i < 8; i++) if (col >= pp.cum[i + 1]) z = i + 1;
    int nb = col - pp.cum[z];
    const float* __restrict__ W = pp.W[z];
    unsigned short* __restrict__ WT = pp.WT[z];
    int N = pp.N[z];
    int kb32 = kb * 32, nb32 = nb * 32;
    __shared__ float tile[32][33];
    int tx = tid & 31, ty = tid >> 5;
    for (int i = ty; i < 32; i += 8) {
      int n = nb32 + tx;
      tile[i][tx] = (n < N) ? W[(size_t)(kb32 + i) * N + n] : 0.f;
    }
    __syncthreads();
    for (int i = ty; i < 32; i += 8) {
      int n = nb32 + i, k = kb32 + tx;
      if (n < N) WT[(size_t)n * 768 + k] = f2bf(tile[tx][i]);
    }
  } else if (b < 4616) {  // ---- adapter f32 -> bf16
    for (int i = (b - 2568) * 256 + tid; i < pp.n4; i += 2048 * 256) {
      float4 v = ((const float4*)pp.adapter)[i];
      ushort4 o;
      o.x = f2bf(v.x); o.y = f2bf(v.y); o.z = f2bf(v.z); o.w = f2bf(v.w);
      ((ushort4*)pp.adbf)[i] = o;
    }
  } else if (b < 5192) {  // ---- vit LN -> bf16
    int wid = (b - 4616) * 4 + (tid >> 6);
    int lane = tid & 63;
    if (wid >= LQ_VIT) return;
    const float* row = pp.vit + (size_t)wid * 768;
    float x[12]; float s = 0.f;
#pragma unroll
    for (int j = 0; j < 12; j++) { x[j] = row[lane + j * 64]; s += x[j]; }
#pragma unroll
    for (int o = 32; o >= 1; o >>= 1) s += __shfl_xor(s, o);
    float mean = s * (1.f / 768.f);
    float v = 0.f;
#pragma unroll
    for (int j = 0; j < 12; j++) { float d = x[j] - mean; v += d * d; }
#pragma unroll
    for (int o = 32; o >= 1; o >>= 1) v += __shfl_xor(v, o);
    float rs = rsqrtf(v * (1.f / 768.f) + 1e-6f);
#pragma unroll
    for (int j = 0; j < 12; j++) {
      int c = lane + j * 64;
      pp.qln[(size_t)wid * 768 + c] = f2bf((x[j] - mean) * rs * pp.qg[c] + pp.qb[c]);
    }
  } else {  // ---- bias concat
    for (int i = tid; i < 840; i += 256) {
      if (i < 144) pp.bci[i] = pp.isv[i];
      else if (i < 216) pp.bci[i] = pp.iav[i - 144];
      if (i < 768) pp.bbig[i] = pp.ibv[i];
      else if (i < 816) pp.bbig[i] = pp.esv[i - 768];
      else pp.bbig[i] = pp.eav[i - 816];
    }
  }
}

// ================= big GEMM: BM=128, BN=128, BK=32, 3-buffer pipeline ========
// While computing K-tile t (buf t%3): t+1 fully resident, t+2's loads in
// flight. End-of-step s_waitcnt vmcnt(4) (per-wave: forces t+1's 4 loads,
// leaves t+2's 4 flying). Raw s_barrier (no counter drain). 24 K-steps.
// Swizzle: rows of 32 elems = 4 granules of 8; stored granule = g^((row>>1)&3)
// (2-way quarter-wave aliasing = free). gload_lds writes linear; source addr
// pre-swizzled: sr=lane>>2, sgx=((lane&3)^((lane>>3)&3))*8.
struct GemmTask {
  const unsigned short* A; const unsigned short* BT;
  const float* bias; unsigned short* C;
  int M, N, NT, nwg;
};

__global__ __launch_bounds__(256) void gemm_big_kernel(GemmTask t0, GemmTask t1, int split) {
  __shared__ unsigned short lds[3][(128 + 128) * 32];  // 3 x 16KB

  GemmTask tk = (blockIdx.x < split) ? t0 : t1;
  int id = (blockIdx.x < split) ? blockIdx.x : blockIdx.x - split;
  int nwg = tk.nwg;
  int qq = nwg >> 3, rr = nwg & 7;
  int xcd = id & 7, idx = id >> 3;
  int wg = (xcd < rr ? xcd * (qq + 1) : rr * (qq + 1) + (xcd - rr) * qq) + idx;
  int nt = wg % tk.NT, mt = wg / tk.NT;     // nt-major: A-tile reused across nt
  int m0 = mt * 128, n0 = nt * 128;
  int M = tk.M, N = tk.N;
  const unsigned short* __restrict__ A = tk.A;
  const unsigned short* __restrict__ BT = tk.BT;
  const int K = 768, kT = 24;

  int tid = threadIdx.x;
  int w = tid >> 6, lane = tid & 63;
  int wr = w >> 1, wc = w & 1;
  int frow = lane & 15, ghi = lane >> 4;
  int sr = lane >> 2;                               // staging row in 16-row chunk
  int sgx = (((lane & 3) ^ ((lane >> 3) & 3)) * 8); // staging source elem offset
  int gxr = ((ghi ^ ((frow >> 1) & 3)) * 8);        // read elem offset (row-indep)

  f32x4 acc[4][4] = {};

  auto stage = [&](unsigned short* dst, int k0) {
#pragma unroll
    for (int i = 0; i < 4; i++) {
      int c = w * 4 + i;                 // 16 chunks: 8 A + 8 B, 1KB each
      if (c < 8) {
        int gm = m0 + c * 16 + sr; if (gm >= M) gm = M - 1;
        gload_lds16(&A[(size_t)gm * K + k0 + sgx], &dst[c * 512]);
      } else {
        int gn = n0 + (c - 8) * 16 + sr; if (gn >= N) gn = N - 1;
        gload_lds16(&BT[(size_t)gn * K + k0 + sgx], &dst[c * 512]);
      }
    }
  };

  stage(&lds[0][0], 0);
  stage(&lds[1][0], 32);
  asm volatile("s_waitcnt vmcnt(4)" ::: "memory");  // buf0 landed, buf1 flying
  FENCE();
  __builtin_amdgcn_s_barrier();
  FENCE();

#pragma unroll
  for (int t = 0; t < kT; t++) {
    unsigned short* cb = &lds[t % 3][0];
    if (t + 2 < kT) stage(&lds[(t + 2) % 3][0], (t + 2) << 5);
    const unsigned short* As_ = cb;
    const unsigned short* Bs_ = cb + 128 * 32;
    bf16x8 af[4], bg[4];
#pragma unroll
    for (int m = 0; m < 4; m++)
      af[m] = *(const bf16x8*)&As_[(wr * 64 + m * 16 + frow) * 32 + gxr];
#pragma unroll
    for (int n = 0; n < 4; n++)
      bg[n] = *(const bf16x8*)&Bs_[(wc * 64 + n * 16 + frow) * 32 + gxr];
#pragma unroll
    for (int m = 0; m < 4; m++)
#pragma unroll
      for (int n = 0; n < 4; n++)
        acc[m][n] = __builtin_amdgcn_mfma_f32_16x16x32_bf16(af[m], bg[n], acc[m][n], 0, 0, 0);
    if (t < kT - 1) {
      if (t + 2 < kT) { asm volatile("s_waitcnt vmcnt(4)" ::: "memory"); }
      else            { asm volatile("s_waitcnt vmcnt(0)" ::: "memory"); }
      FENCE();
      __builtin_amdgcn_s_barrier();
      FENCE();
    }
  }

  int orow = (lane >> 4) * 4, ocol = lane & 15;
  unsigned short* C = tk.C;
  const float* bias = tk.bias;
#pragma unroll
  for (int m = 0; m < 4; m++) {
    int gmb = m0 + wr * 64 + m * 16 + orow;
#pragma unroll
    for (int n = 0; n < 4; n++) {
      int gn = n0 + wc * 64 + n * 16 + ocol;
      if (gn < N) {
        float bv = bias[gn];
#pragma unroll
        for (int r = 0; r < 4; r++) {
          int gm = gmb + r;
          if (gm < M) C[(size_t)gm * N + gn] = f2bf(acc[m][n][r] + bv);
        }
      }
    }
  }
}

// ================= mid GEMM: BM=64, BN=128, BK=32, 3-buffer pipeline =========
__global__ __launch_bounds__(256) void gemm_mid_kernel(
    const unsigned short* __restrict__ A, const unsigned short* __restrict__ BT,
    const float* __restrict__ bias, unsigned short* __restrict__ C,
    int M, int N, int NT) {
  __shared__ unsigned short lds[3][(64 + 128) * 32];  // 3 x 12KB

  int nwg = gridDim.x;
  int id = blockIdx.x;
  int qq = nwg >> 3, rr = nwg & 7;
  int xcd = id & 7, idx = id >> 3;
  int wg = (xcd < rr ? xcd * (qq + 1) : rr * (qq + 1) + (xcd - rr) * qq) + idx;
  int nt = wg % NT, mt = wg / NT;
  int m0 = mt * 64, n0 = nt * 128;
  const int K = 768, kT = 24;

  int tid = threadIdx.x;
  int w = tid >> 6, lane = tid & 63;
  int frow = lane & 15, ghi = lane >> 4;
  int sr = lane >> 2;
  int sgx = (((lane & 3) ^ ((lane >> 3) & 3)) * 8);
  int gxr = ((ghi ^ ((frow >> 1) & 3)) * 8);

  f32x4 acc[4][2] = {};

  auto stage = [&](unsigned short* dst, int k0) {
#pragma unroll
    for (int i = 0; i < 3; i++) {
      int c = w * 3 + i;                 // 12 chunks: 4 A + 8 B
      if (c < 4) {
        int gm = m0 + c * 16 + sr; if (gm >= M) gm = M - 1;
        gload_lds16(&A[(size_t)gm * K + k0 + sgx], &dst[c * 512]);
      } else {
        int gn = n0 + (c - 4) * 16 + sr; if (gn >= N) gn = N - 1;
        gload_lds16(&BT[(size_t)gn * K + k0 + sgx], &dst[c * 512]);
      }
    }
  };

  stage(&lds[0][0], 0);
  stage(&lds[1][0], 32);
  asm volatile("s_waitcnt vmcnt(3)" ::: "memory");
  FENCE();
  __builtin_amdgcn_s_barrier();
  FENCE();

#pragma unroll
  for (int t = 0; t < kT; t++) {
    unsigned short* cb = &lds[t % 3][0];
    if (t + 2 < kT) stage(&lds[(t + 2) % 3][0], (t + 2) << 5);
    const unsigned short* As_ = cb;
    const unsigned short* Bs_ = cb + 64 * 32;
    bf16x8 af[4], bg[2];
#pragma unroll
    for (int m = 0; m < 4; m++)
      af[m] = *(const bf16x8*)&As_[(m * 16 + frow) * 32 + gxr];
#pragma unroll
    for (int n = 0; n < 2; n++)
      bg[n] = *(const bf16x8*)&Bs_[(w * 32 + n * 16 + frow) * 32 + gxr];
#pragma unroll
    for (int m = 0; m < 4; m++)
#pragma unroll
      for (int n = 0; n < 2; n++)
        acc[m][n] = __builtin_amdgcn_mfma_f32_16x16x32_bf16(af[m], bg[n], acc[m][n], 0, 0, 0);
    if (t < kT - 1) {
      if (t + 2 < kT) { asm volatile("s_waitcnt vmcnt(3)" ::: "memory"); }
      else            { asm volatile("s_waitcnt vmcnt(0)" ::: "memory"); }
      FENCE();
      __builtin_amdgcn_s_barrier();
      FENCE();
    }
  }

  int orow = (lane >> 4) * 4, ocol = lane & 15;
#pragma unroll
  for (int m = 0; m < 4; m++) {
    int gmb = m0 + m * 16 + orow;
#pragma unroll
    for (int n = 0; n < 2; n++) {
      int gn = n0 + w * 32 + n * 16 + ocol;
      if (gn < N) {
        float bv = bias[gn];
#pragma unroll
        for (int r = 0; r < 4; r++) {
          int gm = gmb + r;
          if (gm < M) C[(size_t)gm * N + gn] = f2bf(acc[m][n][r] + bv);
        }
      }
    }
  }
}

// ---------------- fused residual + LayerNorm (attn in bf16) ------------------
__global__ __launch_bounds__(256) void residual_ln_kernel(
    const float* __restrict__ vit, const unsigned short* __restrict__ attn,
    const float* __restrict__ gamma, const float* __restrict__ g,
    const float* __restrict__ b, float* __restrict__ vout,
    unsigned short* __restrict__ vln, int R) {
  int wid = blockIdx.x * 4 + (threadIdx.x >> 6);
  int lane = threadIdx.x & 63;
  if (wid >= R) return;
  const float* ra = vit + (size_t)wid * 768;
  const unsigned short* rb = attn + (size_t)wid * 768;
  float x[12]; float s = 0.f;
#pragma unroll
  for (int j = 0; j < 12; j++) {
    int c = lane + j * 64;
    x[j] = ra[c] + gamma[c] * bf2f(rb[c]);
    vout[(size_t)wid * 768 + c] = x[j];
    s += x[j];
  }
#pragma unroll
  for (int o = 32; o >= 1; o >>= 1) s += __shfl_xor(s, o);
  float mean = s * (1.f / 768.f);
  float v = 0.f;
#pragma unroll
  for (int j = 0; j < 12; j++) { float d = x[j] - mean; v += d * d; }
#pragma unroll
  for (int o = 32; o >= 1; o >>= 1) v += __shfl_xor(v, o);
  float rs = rsqrtf(v * (1.f / 768.f) + 1e-6f);
#pragma unroll
  for (int j = 0; j < 12; j++) {
    int c = lane + j * 64;
    vln[(size_t)wid * 768 + c] = f2bf((x[j] - mean) * rs * g[c] + b[c]);
  }
}

// ---------------- add + LayerNorm -> f32 out (Xb in bf16) --------------------
__global__ __launch_bounds__(256) void add_ln_f32_kernel(
    const float* __restrict__ Xa, const unsigned short* __restrict__ Xb,
    const float* __restrict__ g, const float* __restrict__ b,
    float* __restrict__ out, int R) {
  int wid = blockIdx.x * 4 + (threadIdx.x >> 6);
  int lane = threadIdx.x & 63;
  if (wid >= R) return;
  const float* ra = Xa + (size_t)wid * 768;
  const unsigned short* rb = Xb + (size_t)wid * 768;
  float x[12]; float s = 0.f;
#pragma unroll
  for (int j = 0; j < 12; j++) {
    int c = lane + j * 64;
    x[j] = ra[c] + bf2f(rb[c]); s += x[j];
  }
#pragma unroll
  for (int o = 32; o >= 1; o >>= 1) s += __shfl_xor(s, o);
  float mean = s * (1.f / 768.f);
  float v = 0.f;
#pragma unroll
  for (int j = 0; j < 12; j++) { float d = x[j] - mean; v += d * d; }
#pragma unroll
  for (int o = 32; o >= 1; o >>= 1) v += __shfl_xor(v, o);
  float rs = rsqrtf(v * (1.f / 768.f) + 1e-6f);
#pragma unroll
  for (int j = 0; j < 12; j++) {
    int c = lane + j * 64;
    out[(size_t)wid * 768 + c] = (x[j] - mean) * rs * g[c] + b[c];
  }
}

// ---------------- deformable samplers (bf16 tensors) -------------------------
__global__ __launch_bounds__(256) void sampler_inj_kernel(
    const float* __restrict__ ref, const unsigned short* __restrict__ sa,
    const unsigned short* __restrict__ v, unsigned short* __restrict__ out, int vst) {
  int gw = (blockIdx.x * 256 + threadIdx.x) >> 6;
  int lane = threadIdx.x & 63;
  int q = gw / 3, hp = gw - q * 3;
  if (q >= LQ_VIT) return;
  int h = hp * 2 + (lane >> 5);
  int c = h * 128 + (lane & 31) * 4;
  float rx = ref[q * 2], ry = ref[q * 2 + 1];
  const unsigned short* row = sa + (size_t)q * 216;
  float lg[12]; float mx = -1e30f;
#pragma unroll
  for (int i = 0; i < 12; i++) { lg[i] = bf2f(row[144 + h * 12 + i]); mx = fmaxf(mx, lg[i]); }
  float s = 0.f;
#pragma unroll
  for (int i = 0; i < 12; i++) { lg[i] = __expf(lg[i] - mx); s += lg[i]; }
  float inv = 1.f / s;
  f32x4 acc = {0.f, 0.f, 0.f, 0.f};
  const int LW[3] = {96, 48, 24};
  const int LS[3] = {0, 9216, 11520};
#pragma unroll
  for (int l = 0; l < 3; l++) {
    const int Wl = LW[l], st = LS[l], Wm = Wl - 1;
    const float Wf = (float)Wl;
#pragma unroll
    for (int p = 0; p < 4; p++) {
      int ob = ((h * 3 + l) * 4 + p) * 2;
      float ix = fmaf(rx, Wf, bf2f(row[ob])) - 0.5f;
      float iy = fmaf(ry, Wf, bf2f(row[ob + 1])) - 0.5f;
      float x0f = floorf(ix), y0f = floorf(iy);
      float wx = ix - x0f, wy = iy - y0f;
      int x0 = (int)x0f, y0 = (int)y0f;
      float aw = lg[l * 4 + p] * inv;
      float wy0 = (1.f - wy) * aw, wy1 = wy * aw;
      float w00 = (1.f - wx) * wy0, w01 = wx * wy0;
      float w10 = (1.f - wx) * wy1, w11 = wx * wy1;
      bool xv0 = (unsigned)x0 < (unsigned)Wl, xv1 = (unsigned)(x0 + 1) < (unsigned)Wl;
      bool yv0 = (unsigned)y0 < (unsigned)Wl, yv1 = (unsigned)(y0 + 1) < (unsigned)Wl;
      w00 = (xv0 && yv0) ? w00 : 0.f;
      w01 = (xv1 && yv0) ? w01 : 0.f;
      w10 = (xv0 && yv1) ? w10 : 0.f;
      w11 = (xv1 && yv1) ? w11 : 0.f;
      int x0c = min(max(x0, 0), Wm), x1c = min(max(x0 + 1, 0), Wm);
      int y0c = min(max(y0, 0), Wm), y1c = min(max(y0 + 1, 0), Wm);
      const unsigned short* r0 = v + ((size_t)(st + y0c * Wl) * vst + c);
      const unsigned short* r1 = v + ((size_t)(st + y1c * Wl) * vst + c);
      acc += w00 * ld4bf(r0 + (size_t)x0c * vst) + w01 * ld4bf(r0 + (size_t)x1c * vst)
           + w10 * ld4bf(r1 + (size_t)x0c * vst) + w11 * ld4bf(r1 + (size_t)x1c * vst);
    }
  }
  ushort4 o4;
  o4.x = f2bf(acc[0]); o4.y = f2bf(acc[1]); o4.z = f2bf(acc[2]); o4.w = f2bf(acc[3]);
  *(ushort4*)&out[(size_t)q * 768 + c] = o4;
}

__global__ __launch_bounds__(256) void sampler_ext_kernel(
    const float* __restrict__ ref, const unsigned short* __restrict__ sa, int sst,
    const unsigned short* __restrict__ v, unsigned short* __restrict__ out) {
  int gw = (blockIdx.x * 256 + threadIdx.x) >> 6;
  int lane = threadIdx.x & 63;
  int q = gw / 3, hp = gw - q * 3;
  if (q >= NA_ADA) return;
  int h = hp * 2 + (lane >> 5);
  int c = h * 128 + (lane & 31) * 4;
  float rx = ref[q * 2], ry = ref[q * 2 + 1];
  const unsigned short* row = sa + (size_t)q * sst;
  float lg[4]; float mx = -1e30f;
#pragma unroll
  for (int p = 0; p < 4; p++) { lg[p] = bf2f(row[48 + h * 4 + p]); mx = fmaxf(mx, lg[p]); }
  float s = 0.f;
#pragma unroll
  for (int p = 0; p < 4; p++) { lg[p] = __expf(lg[p] - mx); s += lg[p]; }
  float inv = 1.f / s;
  f32x4 acc = {0.f, 0.f, 0.f, 0.f};
#pragma unroll
  for (int p = 0; p < 4; p++) {
    int ob = (h * 4 + p) * 2;
    float ix = fmaf(rx, 48.f, bf2f(row[ob])) - 0.5f;
    float iy = fmaf(ry, 48.f, bf2f(row[ob + 1])) - 0.5f;
    float x0f = floorf(ix), y0f = floorf(iy);
    float wx = ix - x0f, wy = iy - y0f;
    int x0 = (int)x0f, y0 = (int)y0f;
    float aw = lg[p] * inv;
    float wy0 = (1.f - wy) * aw, wy1 = wy * aw;
    float w00 = (1.f - wx) * wy0, w01 = wx * wy0;
    float w10 = (1.f - wx) * wy1, w11 = wx * wy1;
    bool xv0 = (unsigned)x0 < 48u, xv1 = (unsigned)(x0 + 1) < 48u;
    bool yv0 = (unsigned)y0 < 48u, yv1 = (unsigned)(y0 + 1) < 48u;
    w00 = (xv0 && yv0) ? w00 : 0.f;
    w01 = (xv1 && yv0) ? w01 : 0.f;
    w10 = (xv0 && yv1) ? w10 : 0.f;
    w11 = (xv1 && yv1) ? w11 : 0.f;
    int x0c = min(max(x0, 0), 47), x1c = min(max(x0 + 1, 0), 47);
    int y0c = min(max(y0, 0), 47), y1c = min(max(y0 + 1, 0), 47);
    const unsigned short* r0 = v + ((size_t)(y0c * 48) * 768 + c);
    const unsigned short* r1 = v + ((size_t)(y1c * 48) * 768 + c);
    acc += w00 * ld4bf(r0 + (size_t)x0c * 768) + w01 * ld4bf(r0 + (size_t)x1c * 768)
         + w10 * ld4bf(r1 + (size_t)x0c * 768) + w11 * ld4bf(r1 + (size_t)x1c * 768);
  }
  ushort4 o4;
  o4.x = f2bf(acc[0]); o4.y = f2bf(acc[1]); o4.z = f2bf(acc[2]); o4.w = f2bf(acc[3]);
  *(ushort4*)&out[(size_t)q * 768 + c] = o4;
}

extern "C" void kernel_launch(void* const* d_in, const int* in_sizes, int n_in,
                              void* d_out, int out_size, void* d_ws, size_t ws_size,
                              hipStream_t stream) {
  (void)in_sizes; (void)n_in; (void)out_size; (void)ws_size;
  const float* vit      = (const float*)d_in[0];
  const float* adapter  = (const float*)d_in[1];
  const float* ref1     = (const float*)d_in[2];
  const float* ref2     = (const float*)d_in[3];
  const float* inj_qn_g = (const float*)d_in[4];
  const float* inj_qn_b = (const float*)d_in[5];
  const float* inj_Wv   = (const float*)d_in[6];
  const float* inj_bv   = (const float*)d_in[7];
  const float* inj_Ws   = (const float*)d_in[8];
  const float* inj_bs   = (const float*)d_in[9];
  const float* inj_Wa   = (const float*)d_in[10];
  const float* inj_ba   = (const float*)d_in[11];
  const float* inj_Wo   = (const float*)d_in[12];
  const float* inj_bo   = (const float*)d_in[13];
  const float* inj_gamma= (const float*)d_in[14];
  const float* ext_vn_g = (const float*)d_in[15];
  const float* ext_vn_b = (const float*)d_in[16];
  const float* ext_qn_g = (const float*)d_in[17];
  const float* ext_qn_b = (const float*)d_in[18];
  const float* ext_Wv   = (const float*)d_in[19];
  const float* ext_bv   = (const float*)d_in[20];
  const float* ext_Ws   = (const float*)d_in[21];
  const float* ext_bs   = (const float*)d_in[22];
  const float* ext_Wa   = (const float*)d_in[23];
  const float* ext_ba   = (const float*)d_in[24];
  const float* ext_Wo   = (const float*)d_in[25];
  const float* ext_bo   = (const float*)d_in[26];

  size_t cur = 0;
  auto take = [&](size_t bytes) {
    void* p = (char*)d_ws + cur;
    cur += (bytes + 255) & ~(size_t)255;
    return p;
  };
  unsigned short* WBIG = (unsigned short*)take((size_t)840 * 768 * 2);
  unsigned short* WTIO = (unsigned short*)take((size_t)768 * 768 * 2);
  unsigned short* WTEV = (unsigned short*)take((size_t)768 * 768 * 2);
  unsigned short* WTEO = (unsigned short*)take((size_t)768 * 768 * 2);
  unsigned short* WSAI = (unsigned short*)take((size_t)216 * 768 * 2);
  float* BCI  = (float*)take((size_t)216 * 4);
  float* BBIG = (float*)take((size_t)840 * 4);
  unsigned short* ADBF = (unsigned short*)take((size_t)NA_ADA * 768 * 2);
  unsigned short* QLN  = (unsigned short*)take((size_t)LQ_VIT * 768 * 2);
  unsigned short* CBIG = (unsigned short*)take((size_t)NA_ADA * 840 * 2);  // [v_inj | sae]
  unsigned short* SAI  = (unsigned short*)take((size_t)LQ_VIT * 216 * 2);
  unsigned short* SAMPI= (unsigned short*)take((size_t)LQ_VIT * 768 * 2);
  unsigned short* ATTNI= (unsigned short*)take((size_t)LQ_VIT * 768 * 2);
  unsigned short* VLN  = (unsigned short*)take((size_t)LQ_VIT * 768 * 2);
  unsigned short* VEXT = (unsigned short*)take((size_t)LQ_VIT * 768 * 2);
  unsigned short* SAMPE = ADBF;   // adapter_bf16 dead after big GEMM 1
  unsigned short* ATTN2 = CBIG;   // CBIG dead after sampler_ext

  float* out_vit = (float*)d_out;
  float* out_ada = out_vit + (size_t)LQ_VIT * 768;

  PrepPack pp;
  pp.W[0] = inj_Wv; pp.WT[0] = WBIG;               pp.N[0] = 768;
  pp.W[1] = ext_Ws; pp.WT[1] = WBIG + 768 * 768;   pp.N[1] = 48;
  pp.W[2] = ext_Wa; pp.WT[2] = WBIG + 816 * 768;   pp.N[2] = 24;
  pp.W[3] = inj_Wo; pp.WT[3] = WTIO;               pp.N[3] = 768;
  pp.W[4] = ext_Wv; pp.WT[4] = WTEV;               pp.N[4] = 768;
  pp.W[5] = ext_Wo; pp.WT[5] = WTEO;               pp.N[5] = 768;
  pp.W[6] = inj_Ws; pp.WT[6] = WSAI;               pp.N[6] = 144;
  pp.W[7] = inj_Wa; pp.WT[7] = WSAI + 144 * 768;   pp.N[7] = 72;
  int cum = 0;
  for (int i = 0; i < 8; i++) { pp.cum[i] = cum; cum += (pp.N[i] + 31) / 32; }
  pp.cum[8] = cum;  // 107
  pp.adapter = adapter; pp.adbf = ADBF; pp.n4 = (NA_ADA * 768) / 4;
  pp.vit = vit; pp.qg = inj_qn_g; pp.qb = inj_qn_b; pp.qln = QLN;
  pp.isv = inj_bs; pp.iav = inj_ba; pp.ibv = inj_bv;
  pp.esv = ext_bs; pp.eav = ext_ba;
  pp.bci = BCI; pp.bbig = BBIG;
  prep_kernel<<<5193, 256, 0, stream>>>(pp);

  // launch 2: big GEMM 1 (v_inj + ext S/A, N=840) packed with SAI GEMM (N=216)
  GemmTask tA, tB;
  tA.A = ADBF; tA.BT = WBIG; tA.bias = BBIG; tA.C = CBIG;
  tA.M = NA_ADA; tA.N = 840; tA.NT = 7; tA.nwg = 95 * 7;
  tB.A = QLN; tB.BT = WSAI; tB.bias = BCI; tB.C = SAI;
  tB.M = LQ_VIT; tB.N = 216; tB.NT = 2; tB.nwg = 18 * 2;
  gemm_big_kernel<<<95 * 7 + 18 * 2, 256, 0, stream>>>(tA, tB, 95 * 7);

  sampler_inj_kernel<<<1728, 256, 0, stream>>>(ref1, SAI, CBIG, SAMPI, 840);

  gemm_mid_kernel<<<36 * 6, 256, 0, stream>>>(SAMPI, WTIO, inj_bo, ATTNI, LQ_VIT, 768, 6);
  residual_ln_kernel<<<576, 256, 0, stream>>>(vit, ATTNI, inj_gamma, ext_vn_g, ext_vn_b,
                                              out_vit, VLN, LQ_VIT);
  gemm_mid_kernel<<<36 * 6, 256, 0, stream>>>(VLN, WTEV, ext_bv, VEXT, LQ_VIT, 768, 6);

  sampler_ext_kernel<<<9072, 256, 0, stream>>>(ref2, CBIG + 768, 840, VEXT, SAMPE);

  GemmTask tC;
  tC.A = SAMPE; tC.BT = WTEO; tC.bias = ext_bo; tC.C = ATTN2;
  tC.M = NA_ADA; tC.N = 768; tC.NT = 6; tC.nwg = 95 * 6;
  gemm_big_kernel<<<95 * 6, 256, 0, stream>>>(tC, tC, 95 * 6);

  add_ln_f32_kernel<<<3024, 256, 0, stream>>>(adapter, ATTN2, ext_qn_g, ext_qn_b, out_ada, NA_ADA);
}